// Round 3
// baseline (130.501 us; speedup 1.0000x reference)
//
#include <hip/hip_runtime.h>

#define CC    14            // num labels
#define MAXT  13            // max trials
#define RPB   32            // rows per block
#define TPB   256
#define IPB   (RPB * CC)    // 448 items per block
#define UFL   (RPB * CC * MAXT)  // 5824 floats of rand_u per tile
#define RAMP_CAP 1.8f

__global__ __launch_bounds__(TPB) void rwl_kernel(
    const float* __restrict__ inp, const int* __restrict__ target,
    const float* __restrict__ S, const float* __restrict__ rand_u,
    float* __restrict__ out, int B)
{
    __shared__ __align__(16) float s_u[UFL];        // 23296 B
    __shared__ __align__(16) float s_x[RPB * CC];   // 1792 B
    __shared__ unsigned s_posm[RPB];
    __shared__ float    s_fnn[RPB];
    __shared__ int      s_nn[RPB];
    __shared__ float    s_si[RPB];
    __shared__ float    s_w[16];                    // weight by num_trials-1
    __shared__ float    s_red[4];

    const int tid  = threadIdx.x;
    const int base = blockIdx.x * RPB;

    // ---- Phase A: coalesced float4 staging of the tile (lane-contiguous) ----
    {
        const int rows = min(RPB, B - base);
        const int uq = (rows * CC * MAXT) / 4;          // float4 count avail
        const float4* gu = (const float4*)(rand_u + (size_t)base * (CC * MAXT));
        float4* su = (float4*)s_u;
        #pragma unroll
        for (int i = 0; i < 6; ++i) {                   // 1456 = 5*256 + 176
            int idx = tid + i * TPB;
            if (idx < uq) su[idx] = gu[idx];
        }
        const int xq = (rows * CC) / 4;                 // 112
        const float4* gx = (const float4*)(inp + (size_t)base * CC);
        float4* sx = (float4*)s_x;
        if (tid < xq) sx[tid] = gx[tid];
    }
    if (tid == 0) {
        // harmonic cumsum in reference fp32 order, then weight LUT by nt
        float L[14]; float a = 0.f;
        #pragma unroll
        for (int rr = 1; rr <= 14; ++rr) { a += 1.0f / (float)rr; L[rr - 1] = a; }
        #pragma unroll
        for (int i = 1; i <= 13; ++i) s_w[i - 1] = L[13 / i];   // all compile-time
    }

    // ---- Phase B: per-row masks (overlaps with staging loads in flight) ----
    if (tid < RPB && base + tid < B) {
        const int row = base + tid;
        const int* trow = target + (size_t)row * CC;
        unsigned pm = 0; int nn = 0;
        #pragma unroll
        for (int k = 0; k < CC; ++k) {
            if (trow[k] != 0) pm |= (1u << k); else ++nn;
        }
        s_posm[tid] = pm;
        s_nn[tid]   = nn;
        s_fnn[tid]  = (float)nn;
        s_si[tid]   = (row <= 14) ? 1.0f : S[row - 14];
    }
    __syncthreads();

    // ---- Phase C: one (row,label) item per thread-slot, branch-lean ----
    float acc = 0.f;
    #pragma unroll
    for (int w = 0; w < 2; ++w) {
        const int g = tid + w * TPB;
        if (g < IPB && base + g / CC < B) {
            const int r = g / CC, j = g - r * CC;
            const float    xj = s_x[r * CC + j];
            const unsigned pm = s_posm[r];
            const int      nn = s_nn[r];
            const bool    pos = (pm >> j) & 1u;

            float kap = pos ? fminf(fmaxf(1.0f - xj, 0.f), RAMP_CAP) : 1.0f;
            float v = 2.0f * kap;                       // KAPPA = 2

            if (pos && nn > 0) {
                // one pass over the row: neg_sum + resolving-negative bitmask
                float nsum = 0.f; unsigned gm = 0; int cnt = 0;
                #pragma unroll
                for (int k = 0; k < CC; ++k) {
                    if (!((pm >> k) & 1u)) {
                        float xk = s_x[r * CC + k];
                        nsum += fminf(fmaxf(xj - xk, 0.f), RAMP_CAP);
                        if ((1.0f - xj) + xk >= 0.f) gm |= (1u << cnt);
                        ++cnt;
                    }
                }
                // 13 trials -> resolve bit vector, first set bit = num_trials-1
                const float fnn = s_fnn[r];
                const int   ub  = (r * CC + j) * MAXT;
                unsigned bits = 0;
                #pragma unroll
                for (int t = 0; t < MAXT; ++t) {
                    int ti = (int)(s_u[ub + t] * fnn);  // trunc == astype(int32)
                    ti = ti < 0 ? 0 : ti;
                    ti = ti > nn - 1 ? nn - 1 : ti;
                    bits |= ((gm >> ti) & 1u) << t;
                }
                const int nt = bits ? __ffs(bits) : MAXT;
                v += s_w[nt - 1] * nsum;
            }
            acc += s_si[r] * v;
        }
    }

    // ---- block reduction: wave shuffle, LDS across 4 waves, 1 atomic ----
    #pragma unroll
    for (int off = 32; off > 0; off >>= 1)
        acc += __shfl_down(acc, off, 64);
    const int wave = tid >> 6;
    if ((tid & 63) == 0) s_red[wave] = acc;
    __syncthreads();
    if (tid == 0)
        atomicAdd(out, s_red[0] + s_red[1] + s_red[2] + s_red[3]);
}

extern "C" void kernel_launch(void* const* d_in, const int* in_sizes, int n_in,
                              void* d_out, int out_size, void* d_ws, size_t ws_size,
                              hipStream_t stream) {
    const float* inp    = (const float*)d_in[0];
    const int*   target = (const int*)d_in[1];
    const float* S      = (const float*)d_in[2];
    const float* ru     = (const float*)d_in[3];
    float*       out    = (float*)d_out;
    const int B = in_sizes[2];   // S has B elements

    // d_out is poisoned and not re-zeroed between replays: zero it each call
    hipMemsetAsync(out, 0, sizeof(float), stream);

    const int blocks = (B + RPB - 1) / RPB;
    rwl_kernel<<<blocks, TPB, 0, stream>>>(inp, target, S, ru, out, B);
}

// Round 4
// 55.561 us; speedup vs baseline: 2.3488x; 2.3488x over previous
//
#include <hip/hip_runtime.h>

#define CC   14      // num labels
#define MAXT 13      // max trials
#define TPB  256     // one row per thread
#define RAMP_CAP 1.8f

__global__ __launch_bounds__(TPB) void rwl_kernel(
    const float* __restrict__ inp, const int* __restrict__ target,
    const float* __restrict__ S, const float* __restrict__ rand_u,
    float* __restrict__ out, int B)
{
    __shared__ float s_red[4];
    const int tid = threadIdx.x;
    const int row = blockIdx.x * TPB + tid;

    // harmonic numbers as compile-time fp32 chain (reference cumsum order)
    constexpr float H2  = 1.0f + 0.5f;
    constexpr float H3  = H2  + (1.0f/3.0f);
    constexpr float H4  = H3  + 0.25f;
    constexpr float H5  = H4  + 0.2f;
    constexpr float H6  = H5  + (1.0f/6.0f);
    constexpr float H7  = H6  + (1.0f/7.0f);
    constexpr float H8  = H7  + 0.125f;
    constexpr float H9  = H8  + (1.0f/9.0f);
    constexpr float H10 = H9  + 0.1f;
    constexpr float H11 = H10 + (1.0f/11.0f);
    constexpr float H12 = H11 + (1.0f/12.0f);
    constexpr float H13 = H12 + (1.0f/13.0f);
    constexpr float H14 = H13 + (1.0f/14.0f);
    // weight(nt) = L[13 // nt], L[i] = H_{i+1}

    float total = 0.f;
    if (row < B) {
        const float* xrow = inp + (size_t)row * CC;
        const int*   trow = target + (size_t)row * CC;

        float x[CC];
        #pragma unroll
        for (int k = 0; k < CC; ++k) x[k] = xrow[k];

        unsigned pm = 0; float kap = 0.f;
        #pragma unroll
        for (int k = 0; k < CC; ++k) {
            if (trow[k] != 0) {
                pm |= (1u << k);
                kap += fminf(fmaxf(1.0f - x[k], 0.f), RAMP_CAP);
            } else {
                kap += 1.0f;          // clip(1 - 0*x, 0, 1.8) = 1
            }
        }
        const int nn = CC - __popc(pm);

        float lw = 0.f;
        if (pm != 0u && nn > 0) {
            const float fnn = (float)nn;
            const float* pu = rand_u + (size_t)row * (CC * MAXT);
            #pragma unroll
            for (int j = 0; j < CC; ++j) {
                if ((pm >> j) & 1u) {
                    const float* uj = pu + j * MAXT;
                    // 8 independent trial loads up-front (P(need more) ~ 1e-5)
                    float uv[8];
                    #pragma unroll
                    for (int t = 0; t < 8; ++t) uv[t] = uj[t];

                    // one pass over row: neg_sum + resolving-negative bitmask
                    const float m1 = 1.0f - x[j];
                    float nsum = 0.f; unsigned gm = 0; int cnt = 0;
                    #pragma unroll
                    for (int k = 0; k < CC; ++k) {
                        if (!((pm >> k) & 1u)) {
                            nsum += fminf(fmaxf(x[j] - x[k], 0.f), RAMP_CAP);
                            if (m1 + x[k] >= 0.f) gm |= (1u << cnt);  // ref assoc
                            ++cnt;
                        }
                    }

                    unsigned bits = 0;
                    #pragma unroll
                    for (int t = 0; t < 8; ++t) {
                        int ti = (int)(uv[t] * fnn);     // trunc == astype(int32)
                        ti = ti < 0 ? 0 : ti;
                        ti = ti > nn - 1 ? nn - 1 : ti;
                        bits |= ((gm >> ti) & 1u) << t;
                    }
                    if (bits == 0u) {                     // rare tail: trials 8..12
                        #pragma unroll
                        for (int t = 8; t < MAXT; ++t) {
                            int ti = (int)(uj[t] * fnn);
                            ti = ti < 0 ? 0 : ti;
                            ti = ti > nn - 1 ? nn - 1 : ti;
                            bits |= ((gm >> ti) & 1u) << t;
                        }
                    }
                    const int nt = bits ? __ffs(bits) : MAXT;
                    const float wt = (nt == 1) ? H14 : (nt == 2) ? H7
                                   : (nt == 3) ? H5  : (nt == 4) ? H4
                                   : (nt <= 6) ? H3  : H2;
                    lw += wt * nsum;
                }
            }
        }
        const float si = (row <= 14) ? 1.0f : S[row - 14];
        total = si * (lw + 2.0f * kap);
    }

    // block reduction: wave shuffle, LDS across 4 waves, 1 atomic per block
    #pragma unroll
    for (int off = 32; off > 0; off >>= 1)
        total += __shfl_down(total, off, 64);
    const int wave = tid >> 6;
    if ((tid & 63) == 0) s_red[wave] = total;
    __syncthreads();
    if (tid == 0)
        atomicAdd(out, s_red[0] + s_red[1] + s_red[2] + s_red[3]);
}

extern "C" void kernel_launch(void* const* d_in, const int* in_sizes, int n_in,
                              void* d_out, int out_size, void* d_ws, size_t ws_size,
                              hipStream_t stream) {
    const float* inp    = (const float*)d_in[0];
    const int*   target = (const int*)d_in[1];
    const float* S      = (const float*)d_in[2];
    const float* ru     = (const float*)d_in[3];
    float*       out    = (float*)d_out;
    const int B = in_sizes[2];   // S has B elements

    // d_out is poisoned and not re-zeroed between replays: zero it each call
    hipMemsetAsync(out, 0, sizeof(float), stream);

    const int blocks = (B + TPB - 1) / TPB;
    rwl_kernel<<<blocks, TPB, 0, stream>>>(inp, target, S, ru, out, B);
}

// Round 5
// 51.128 us; speedup vs baseline: 2.5524x; 1.0867x over previous
//
#include <hip/hip_runtime.h>

#define CC   14      // num labels
#define MAXT 13      // max trials
#define TPB  256
#define RAMP_CAP 1.8f

// harmonic numbers, fp32 chain in reference cumsum order
constexpr float H2  = 1.0f + 0.5f;
constexpr float H3  = H2  + (1.0f/3.0f);
constexpr float H4  = H3  + 0.25f;
constexpr float H5  = H4  + 0.2f;
constexpr float H6  = H5  + (1.0f/6.0f);
constexpr float H7  = H6  + (1.0f/7.0f);
constexpr float H14 = H7 + 0.125f + (1.0f/9.0f) + 0.1f + (1.0f/11.0f)
                         + (1.0f/12.0f) + (1.0f/13.0f) + (1.0f/14.0f);

// one positive label's trial resolution; J and PAR compile-time so the
// float4 alignment phase SH and all extraction indices are static.
template<int PAR, int J>
__device__ __forceinline__ void do_label(unsigned pm, int nn, float fnn,
                                         const float* __restrict__ rowF,
                                         const float (&x)[CC], float& lw)
{
    if ((pm >> J) & 1u) {
        constexpr int SH = (J + 2 * PAR) & 3;       // (182*row + 13J) mod 4
        const float* qp = rowF + (13 * J - SH);      // 16B-aligned by construction
        float4 q0 = *(const float4*)(qp);
        float4 q1 = *(const float4*)(qp + 4);
        float4 q2 = *(const float4*)(qp + 8);
        const float e[12] = {q0.x,q0.y,q0.z,q0.w, q1.x,q1.y,q1.z,q1.w,
                             q2.x,q2.y,q2.z,q2.w};

        // one pass over row: neg_sum + resolving-negative bitmask (k-order)
        const float m1 = 1.0f - x[J];
        float nsum = 0.f; unsigned gm = 0; int cnt = 0;
        #pragma unroll
        for (int k = 0; k < CC; ++k) {
            if (!((pm >> k) & 1u)) {
                nsum += fminf(fmaxf(x[J] - x[k], 0.f), RAMP_CAP);
                if (m1 + x[k] >= 0.f) gm |= (1u << cnt);   // ref association
                ++cnt;
            }
        }

        unsigned bits = 0;
        #pragma unroll
        for (int t = 0; t < 8; ++t) {                // trials 0..7, static idx
            int ti = (int)(e[SH + t] * fnn);         // trunc == astype(int32)
            ti = ti < 0 ? 0 : ti;
            ti = ti > nn - 1 ? nn - 1 : ti;
            bits |= ((gm >> ti) & 1u) << t;
        }
        if (bits == 0u) {                            // rare tail: P ~ 1e-5
            #pragma unroll
            for (int t = 8; t < MAXT; ++t) {
                int ti = (int)(rowF[13 * J + t] * fnn);
                ti = ti < 0 ? 0 : ti;
                ti = ti > nn - 1 ? nn - 1 : ti;
                bits |= ((gm >> ti) & 1u) << t;
            }
        }
        const int nt = bits ? __ffs(bits) : MAXT;    // num_trials
        const float wt = (nt == 1) ? H14 : (nt == 2) ? H7
                       : (nt == 3) ? H5  : (nt == 4) ? H4
                       : (nt <= 6) ? H3  : H2;       // L[13 // nt]
        lw += wt * nsum;
    }
}

template<int PAR>
__device__ __forceinline__ float row_contrib(int row,
    const float* __restrict__ inp, const int* __restrict__ target,
    const float* __restrict__ S, const float* __restrict__ rand_u)
{
    // inp row: aligned vector loads, phase = 2*PAR (14*row mod 4)
    float x[CC];
    {
        const float* b = inp + (size_t)row * CC;
        if constexpr (PAR == 0) {
            float4 a0 = *(const float4*)(b);
            float4 a1 = *(const float4*)(b + 4);
            float4 a2 = *(const float4*)(b + 8);
            float2 a3 = *(const float2*)(b + 12);
            x[0]=a0.x; x[1]=a0.y; x[2]=a0.z; x[3]=a0.w;
            x[4]=a1.x; x[5]=a1.y; x[6]=a1.z; x[7]=a1.w;
            x[8]=a2.x; x[9]=a2.y; x[10]=a2.z; x[11]=a2.w;
            x[12]=a3.x; x[13]=a3.y;
        } else {
            float2 a0 = *(const float2*)(b);
            float4 a1 = *(const float4*)(b + 2);
            float4 a2 = *(const float4*)(b + 6);
            float4 a3 = *(const float4*)(b + 10);
            x[0]=a0.x; x[1]=a0.y;
            x[2]=a1.x; x[3]=a1.y; x[4]=a1.z; x[5]=a1.w;
            x[6]=a2.x; x[7]=a2.y; x[8]=a2.z; x[9]=a2.w;
            x[10]=a3.x; x[11]=a3.y; x[12]=a3.z; x[13]=a3.w;
        }
    }
    int tg[CC];
    {
        const int* b = target + (size_t)row * CC;
        if constexpr (PAR == 0) {
            int4 a0 = *(const int4*)(b);
            int4 a1 = *(const int4*)(b + 4);
            int4 a2 = *(const int4*)(b + 8);
            int2 a3 = *(const int2*)(b + 12);
            tg[0]=a0.x; tg[1]=a0.y; tg[2]=a0.z; tg[3]=a0.w;
            tg[4]=a1.x; tg[5]=a1.y; tg[6]=a1.z; tg[7]=a1.w;
            tg[8]=a2.x; tg[9]=a2.y; tg[10]=a2.z; tg[11]=a2.w;
            tg[12]=a3.x; tg[13]=a3.y;
        } else {
            int2 a0 = *(const int2*)(b);
            int4 a1 = *(const int4*)(b + 2);
            int4 a2 = *(const int4*)(b + 6);
            int4 a3 = *(const int4*)(b + 10);
            tg[0]=a0.x; tg[1]=a0.y;
            tg[2]=a1.x; tg[3]=a1.y; tg[4]=a1.z; tg[5]=a1.w;
            tg[6]=a2.x; tg[7]=a2.y; tg[8]=a2.z; tg[9]=a2.w;
            tg[10]=a3.x; tg[11]=a3.y; tg[12]=a3.z; tg[13]=a3.w;
        }
    }

    unsigned pm = 0; float kap = 0.f;
    #pragma unroll
    for (int k = 0; k < CC; ++k) {
        if (tg[k] != 0) {
            pm |= (1u << k);
            kap += fminf(fmaxf(1.0f - x[k], 0.f), RAMP_CAP);
        } else {
            kap += 1.0f;                 // clip(1 - 0*x, 0, 1.8) = 1
        }
    }
    const int nn = CC - __popc(pm);

    float lw = 0.f;
    if (pm != 0u && nn > 0) {
        const float fnn = (float)nn;
        const float* rowF = rand_u + (size_t)row * (CC * MAXT);
        do_label<PAR, 0>(pm, nn, fnn, rowF, x, lw);
        do_label<PAR, 1>(pm, nn, fnn, rowF, x, lw);
        do_label<PAR, 2>(pm, nn, fnn, rowF, x, lw);
        do_label<PAR, 3>(pm, nn, fnn, rowF, x, lw);
        do_label<PAR, 4>(pm, nn, fnn, rowF, x, lw);
        do_label<PAR, 5>(pm, nn, fnn, rowF, x, lw);
        do_label<PAR, 6>(pm, nn, fnn, rowF, x, lw);
        do_label<PAR, 7>(pm, nn, fnn, rowF, x, lw);
        do_label<PAR, 8>(pm, nn, fnn, rowF, x, lw);
        do_label<PAR, 9>(pm, nn, fnn, rowF, x, lw);
        do_label<PAR,10>(pm, nn, fnn, rowF, x, lw);
        do_label<PAR,11>(pm, nn, fnn, rowF, x, lw);
        do_label<PAR,12>(pm, nn, fnn, rowF, x, lw);
        do_label<PAR,13>(pm, nn, fnn, rowF, x, lw);
    }
    const float si = (row <= 14) ? 1.0f : S[row - 14];
    return si * (lw + 2.0f * kap);
}

__global__ __launch_bounds__(TPB) void rwl_kernel(
    const float* __restrict__ inp, const int* __restrict__ target,
    const float* __restrict__ S, const float* __restrict__ rand_u,
    float* __restrict__ out, int B)
{
    __shared__ float s_red[4];
    const int tid  = threadIdx.x;
    const int pair = blockIdx.x * TPB + tid;
    const int r0 = pair * 2, r1 = r0 + 1;

    float total = 0.f;
    if (r0 < B) total += row_contrib<0>(r0, inp, target, S, rand_u);
    if (r1 < B) total += row_contrib<1>(r1, inp, target, S, rand_u);

    // block reduction: wave shuffle, LDS across 4 waves, 1 atomic per block
    #pragma unroll
    for (int off = 32; off > 0; off >>= 1)
        total += __shfl_down(total, off, 64);
    const int wave = tid >> 6;
    if ((tid & 63) == 0) s_red[wave] = total;
    __syncthreads();
    if (tid == 0)
        atomicAdd(out, s_red[0] + s_red[1] + s_red[2] + s_red[3]);
}

extern "C" void kernel_launch(void* const* d_in, const int* in_sizes, int n_in,
                              void* d_out, int out_size, void* d_ws, size_t ws_size,
                              hipStream_t stream) {
    const float* inp    = (const float*)d_in[0];
    const int*   target = (const int*)d_in[1];
    const float* S      = (const float*)d_in[2];
    const float* ru     = (const float*)d_in[3];
    float*       out    = (float*)d_out;
    const int B = in_sizes[2];   // S has B elements

    // d_out is poisoned and not re-zeroed between replays: zero it each call
    hipMemsetAsync(out, 0, sizeof(float), stream);

    const int pairs  = (B + 1) / 2;
    const int blocks = (pairs + TPB - 1) / TPB;
    rwl_kernel<<<blocks, TPB, 0, stream>>>(inp, target, S, ru, out, B);
}